// Round 10
// baseline (625.095 us; speedup 1.0000x reference)
//
#include <hip/hip_runtime.h>

typedef _Float16 f16;
typedef f16 f16x2 __attribute__((ext_vector_type(2)));
typedef f16 f16x4 __attribute__((ext_vector_type(4)));
typedef f16 f16x8 __attribute__((ext_vector_type(8)));
typedef float f32x4 __attribute__((ext_vector_type(4)));

constexpr int Mdim = 32768, Ndim = 1024, Kdim = 1024;
constexpr int BM = 256, BN = 256, BK = 32;
constexpr int NT = Kdim / BK;   // 32 K-steps

static __device__ inline f16x2 cvt2(float a, float b) {
    return __builtin_bit_cast(f16x2, __builtin_amdgcn_cvt_pkrtz(a, b));
}
static __device__ inline f16x8 pack8(float4 a, float4 b) {
    f16x2 p0 = cvt2(a.x, a.y), p1 = cvt2(a.z, a.w);
    f16x2 p2 = cvt2(b.x, b.y), p3 = cvt2(b.z, b.w);
    f16x4 lo = __builtin_shufflevector(p0, p1, 0, 1, 2, 3);
    f16x4 hi = __builtin_shufflevector(p2, p3, 0, 1, 2, 3);
    return __builtin_shufflevector(lo, hi, 0, 1, 2, 3, 4, 5, 6, 7);
}
static __device__ inline void bar() {          // raw: no vmcnt drain
    asm volatile("" ::: "memory");
    __builtin_amdgcn_s_barrier();
    asm volatile("" ::: "memory");
}
static __device__ inline void lgkm0() {
    asm volatile("s_waitcnt lgkmcnt(0)" ::: "memory");
}

// out[b,n] = fp32(sum_k fp16(x[b,k]) * fp16(w[n,k])) + bias[n]
// (reference's early-termination mask is always-true: tstat >= 0 > TAU never holds)
//
// R10: BK 64->32. Same 256x256 tile (traffic unchanged) but LDS 128->64 KB
// -> 2 blocks/CU (16 waves, 4/SIMD). R2..R9 all plateaued at ~97-130us with
// 2 waves/SIMD: in-wave ds_read->MFMA chains can't overlap without TLP.
// Independent blocks share no barriers -> automatic MFMA/LDS overlap (m114).
// [256][32] f16 rows are conflict-free WITHOUT swizzle: fragment-read start
// banks (16r+4g)%32 tile all 32 banks; staging b128 writes likewise.
__global__ __launch_bounds__(512, 4)
void etrow_gemm(const float* __restrict__ X, const float* __restrict__ W,
                const float* __restrict__ bias, float* __restrict__ out)
{
    __shared__ f16 As[2][BM * BK];   // 16 KB per buffer
    __shared__ f16 Bs[2][BN * BK];   // 64 KB total -> 2 blocks/CU

    // bijective XCD-aware swizzle (512 blocks, 64 per XCD)
    const int bid = blockIdx.x;
    const int cpx = gridDim.x >> 3;
    const int wg  = (bid & 7) * cpx + (bid >> 3);
    const int mIdx = wg >> 2;        // 4 n-tiles, n fastest
    const int nIdx = wg & 3;

    const int tid  = threadIdx.x;
    const int lane = tid & 63;
    const int wave = tid >> 6;            // 0..7
    const int wr   = (wave >> 2) * 128;   // 2m x 4n waves, wave tile 128x64
    const int wc   = (wave & 3) * 64;

    // staging: thread covers 8 f32 (one b128 after cvt) per row, 2 rows/leg
    const int srow = tid >> 2;            // 0..127
    const int sc8  = (tid & 3) * 8;       // f32 col 0/8/16/24

    const float* xthr = X + (size_t)mIdx * BM * Kdim + (size_t)srow * Kdim + sc8;
    const float* wthr = W + (size_t)nIdx * BN * Kdim + (size_t)srow * Kdim + sc8;
    const int wby = srow * 64 + (tid & 3) * 16;   // + pass*8192 (+128 rows)
    const int aby = (wr + (lane & 15)) * 64 + (lane >> 4) * 16;
    const int bby = (wc + (lane & 15)) * 64 + (lane >> 4) * 16;
    char* const Ab = (char*)&As[0][0];
    char* const Bb = (char*)&Bs[0][0];

    float4 sa[4], sb[4];        // [pass*2+half], one in-flight K-step per leg
    f32x4 acc[8][4] = {};

    auto loadA = [&](int kt) {
        const float* p = xthr + kt * BK;
        #pragma unroll
        for (int q = 0; q < 2; ++q) {
            sa[q * 2 + 0] = *(const float4*)(p + (size_t)q * 128 * Kdim);
            sa[q * 2 + 1] = *(const float4*)(p + (size_t)q * 128 * Kdim + 4);
        }
    };
    auto loadB = [&](int kt) {
        const float* p = wthr + kt * BK;
        #pragma unroll
        for (int q = 0; q < 2; ++q) {
            sb[q * 2 + 0] = *(const float4*)(p + (size_t)q * 128 * Kdim);
            sb[q * 2 + 1] = *(const float4*)(p + (size_t)q * 128 * Kdim + 4);
        }
    };
    auto cvtWrA = [&](int off) {
        #pragma unroll
        for (int q = 0; q < 2; ++q)
            *(f16x8*)(Ab + off + wby + q * 8192) = pack8(sa[q * 2], sa[q * 2 + 1]);
    };
    auto cvtWrB = [&](int off) {
        #pragma unroll
        for (int q = 0; q < 2; ++q)
            *(f16x8*)(Bb + off + wby + q * 8192) = pack8(sb[q * 2], sb[q * 2 + 1]);
    };

    auto computeTile = [&](int off) {     // one K=32 step: 12 ds_read, 32 MFMA
        f16x8 bf[4];
        #pragma unroll
        for (int j = 0; j < 4; ++j)
            bf[j] = *(const f16x8*)(Bb + off + bby + j * 1024);
        #pragma unroll
        for (int m = 0; m < 8; ++m) {     // af single-live: keeps VGPR <= 128
            f16x8 af = *(const f16x8*)(Ab + off + aby + m * 1024);
            #pragma unroll
            for (int j = 0; j < 4; ++j)
                acc[m][j] = __builtin_amdgcn_mfma_f32_16x16x32_f16(
                    af, bf[j], acc[m][j], 0, 0, 0);
        }
    };

    // prologue: tile 0 staged; tile 1 loads in flight across the barrier
    loadA(0); cvtWrA(0);
    loadB(0); cvtWrB(0);
    loadA(1); loadB(1);
    lgkm0();
    bar();

    for (int t = 0; t < NT; ++t) {
        const int co = (t & 1) << 14;     // 16 KB buffer stride
        const int no = co ^ 16384;
        // publish tile t+1 (loads one full iteration old -> counted vmcnt),
        // then reuse sa/sb for tile t+2 (WAR keeps order; in flight across bar)
        if (t + 1 < NT) { cvtWrA(no); cvtWrB(no); }
        if (t + 2 < NT) { loadA(t + 2); loadB(t + 2); }
        computeTile(co);
        lgkm0();                          // publish our ds_writes
        bar();                            // raw: global loads stay in flight
    }

    // epilogue: C/D layout col = lane&15, row = (lane>>4)*4 + reg (m89-verified)
    const int col0  = nIdx * BN + wc + (lane & 15);
    const int rbase = mIdx * BM + wr + (lane >> 4) * 4;
    float bv[4];
    #pragma unroll
    for (int n = 0; n < 4; ++n) bv[n] = bias[col0 + n * 16];

    #pragma unroll
    for (int m = 0; m < 8; ++m) {
        #pragma unroll
        for (int j = 0; j < 4; ++j) {
            const int row = rbase + m * 16 + j;
            float* o = out + (size_t)row * Ndim + col0;
            #pragma unroll
            for (int n = 0; n < 4; ++n)
                o[n * 16] = acc[m][n][j] + bv[n];
        }
    }
}

extern "C" void kernel_launch(void* const* d_in, const int* in_sizes, int n_in,
                              void* d_out, int out_size, void* d_ws, size_t ws_size,
                              hipStream_t stream) {
    const float* X  = (const float*)d_in[0];
    const float* W  = (const float*)d_in[1];
    const float* bs = (const float*)d_in[2];
    float* out = (float*)d_out;
    const int grid = (Mdim / BM) * (Ndim / BN);   // 512 blocks
    etrow_gemm<<<grid, 512, 0, stream>>>(X, W, bs, out);
}

// Round 11
// 115.281 us; speedup vs baseline: 5.4224x; 5.4224x over previous
//
#include <hip/hip_runtime.h>

typedef _Float16 f16;
typedef f16 f16x2 __attribute__((ext_vector_type(2)));
typedef f16 f16x4 __attribute__((ext_vector_type(4)));
typedef f16 f16x8 __attribute__((ext_vector_type(8)));
typedef float f32x4 __attribute__((ext_vector_type(4)));

constexpr int Mdim = 32768, Ndim = 1024, Kdim = 1024;
constexpr int BM = 256, BN = 256, BK = 32;
constexpr int NT = Kdim / BK;   // 32 K-steps

static __device__ inline f16x2 cvt2(float a, float b) {
    return __builtin_bit_cast(f16x2, __builtin_amdgcn_cvt_pkrtz(a, b));
}
static __device__ inline f16x8 pack8(float4 a, float4 b) {
    f16x2 p0 = cvt2(a.x, a.y), p1 = cvt2(a.z, a.w);
    f16x2 p2 = cvt2(b.x, b.y), p3 = cvt2(b.z, b.w);
    f16x4 lo = __builtin_shufflevector(p0, p1, 0, 1, 2, 3);
    f16x4 hi = __builtin_shufflevector(p2, p3, 0, 1, 2, 3);
    return __builtin_shufflevector(lo, hi, 0, 1, 2, 3, 4, 5, 6, 7);
}
static __device__ inline void bar() {          // raw: no vmcnt drain
    asm volatile("" ::: "memory");
    __builtin_amdgcn_s_barrier();
    asm volatile("" ::: "memory");
}
static __device__ inline void lgkm0() {
    asm volatile("s_waitcnt lgkmcnt(0)" ::: "memory");
}

// out[b,n] = fp32(sum_k fp16(x[b,k]) * fp16(w[n,k])) + bias[n]
// (reference's early-termination mask is always-true: tstat >= 0 > TAU never holds)
//
// R11: occupancy attack done right. 16 waves (4m x 4n), wave tile 64x64 ->
// acc 64/wave; total regs ~120 <= 128 -> 4 waves/SIMD (R10 failed: 8-wave
// decomposition needs 128 acc alone, and launch_bounds(,4) forced a spill).
// BK=32, LDS 64 KB. Swizzle ((row>>1)&3)<<4: 16 consecutive rows -> 8
// positions x 2 = 2-way (free). R10's unswizzled [256][32] was 4-8 way.
__global__ __launch_bounds__(1024, 4)
void etrow_gemm(const float* __restrict__ X, const float* __restrict__ W,
                const float* __restrict__ bias, float* __restrict__ out)
{
    __shared__ f16 As[2][BM * BK];   // 16 KB per buffer
    __shared__ f16 Bs[2][BN * BK];   // 64 KB total

    // bijective XCD-aware swizzle (512 blocks, 64 per XCD)
    const int bid = blockIdx.x;
    const int cpx = gridDim.x >> 3;
    const int wg  = (bid & 7) * cpx + (bid >> 3);
    const int mIdx = wg >> 2;        // 4 n-tiles, n fastest
    const int nIdx = wg & 3;

    const int tid  = threadIdx.x;
    const int lane = tid & 63;
    const int wave = tid >> 6;            // 0..15
    const int wr   = (wave >> 2) * 64;    // 4m x 4n waves, wave tile 64x64
    const int wc   = (wave & 3) * 64;

    // staging: thread t covers row t>>2, f32 cols (t&3)*8..+7 (one b128 out)
    const int srow = tid >> 2;            // 0..255
    const int sc8  = (tid & 3) * 8;

    const float* xthr = X + (size_t)mIdx * BM * Kdim + (size_t)srow * Kdim + sc8;
    const float* wthr = W + (size_t)nIdx * BN * Kdim + (size_t)srow * Kdim + sc8;
    const int wby = (srow * 64 + (tid & 3) * 16) ^ (((srow >> 1) & 3) << 4);
    // fragment base: row = wr|wc + m*16 + (lane&15); slot = lane>>4
    const int rl   = lane & 15;
    const int aby  = ((wr + rl) * 64 + (lane >> 4) * 16) ^ (((rl >> 1) & 3) << 4);
    const int bby  = ((wc + rl) * 64 + (lane >> 4) * 16) ^ (((rl >> 1) & 3) << 4);
    char* const Ab = (char*)&As[0][0];
    char* const Bb = (char*)&Bs[0][0];

    float4 S0, S1;              // ONE shared 8-f32 staging set (A then B legs)
    f32x4 acc[4][4] = {};       // 64 AGPR

    auto loadA = [&](int kt) {
        S0 = *(const float4*)(xthr + kt * BK);
        S1 = *(const float4*)(xthr + kt * BK + 4);
    };
    auto loadB = [&](int kt) {
        S0 = *(const float4*)(wthr + kt * BK);
        S1 = *(const float4*)(wthr + kt * BK + 4);
    };
    auto cvtWrA = [&](int off) { *(f16x8*)(Ab + off + wby) = pack8(S0, S1); };
    auto cvtWrB = [&](int off) { *(f16x8*)(Bb + off + wby) = pack8(S0, S1); };

    // prologue: tile 0 staged; A(1) in flight across the barrier
    loadA(0); cvtWrA(0);
    loadB(0); cvtWrB(0);
    loadA(1);
    lgkm0();
    bar();

    for (int t = 0; t < NT; ++t) {
        const int co = (t & 1) << 14;     // 16 KB buffer stride
        const int no = co ^ 16384;
        const bool h1 = t + 1 < NT, h2 = t + 2 < NT;

        if (h1) { cvtWrA(no); loadB(t + 1); }   // S: A(t+1) old -> free wait
        // half 1: bf reads + m = 0,1  (covers B(t+1) L2 latency)
        f16x8 bf[4];
        #pragma unroll
        for (int j = 0; j < 4; ++j)
            bf[j] = *(const f16x8*)(Bb + co + bby + j * 1024);
        #pragma unroll
        for (int m = 0; m < 2; ++m) {
            f16x8 af = *(const f16x8*)(Ab + co + aby + m * 1024);
            #pragma unroll
            for (int j = 0; j < 4; ++j)
                acc[m][j] = __builtin_amdgcn_mfma_f32_16x16x32_f16(
                    af, bf[j], acc[m][j], 0, 0, 0);
        }
        if (h1) { cvtWrB(no); }                 // B loaded ~half-iter ago
        if (h2) { loadA(t + 2); }               // X leg: full-iter cover
        // half 2: m = 2,3
        #pragma unroll
        for (int m = 2; m < 4; ++m) {
            f16x8 af = *(const f16x8*)(Ab + co + aby + m * 1024);
            #pragma unroll
            for (int j = 0; j < 4; ++j)
                acc[m][j] = __builtin_amdgcn_mfma_f32_16x16x32_f16(
                    af, bf[j], acc[m][j], 0, 0, 0);
        }
        lgkm0();                          // publish our ds_writes
        bar();                            // raw: global loads stay in flight
    }

    // epilogue: C/D layout col = lane&15, row = (lane>>4)*4 + reg (m89-verified)
    const int col0  = nIdx * BN + wc + (lane & 15);
    const int rbase = mIdx * BM + wr + (lane >> 4) * 4;
    float bv[4];
    #pragma unroll
    for (int n = 0; n < 4; ++n) bv[n] = bias[col0 + n * 16];

    #pragma unroll
    for (int m = 0; m < 4; ++m) {
        #pragma unroll
        for (int j = 0; j < 4; ++j) {
            const int row = rbase + m * 16 + j;
            float* o = out + (size_t)row * Ndim + col0;
            #pragma unroll
            for (int n = 0; n < 4; ++n)
                o[n * 16] = acc[m][n][j] + bv[n];
        }
    }
}

extern "C" void kernel_launch(void* const* d_in, const int* in_sizes, int n_in,
                              void* d_out, int out_size, void* d_ws, size_t ws_size,
                              hipStream_t stream) {
    const float* X  = (const float*)d_in[0];
    const float* W  = (const float*)d_in[1];
    const float* bs = (const float*)d_in[2];
    float* out = (float*)d_out;
    const int grid = (Mdim / BM) * (Ndim / BN);   // 512 blocks
    etrow_gemm<<<grid, 1024, 0, stream>>>(X, W, bs, out);
}